// Round 2
// baseline (232.439 us; speedup 1.0000x reference)
//
#include <hip/hip_runtime.h>
#include <stdint.h>

// HashedInterpolator: 3D hash-grid trilinear interpolation.
// R1: 4 points per thread to raise memory-level parallelism (8 -> 32
// independent table gathers per wave). Position loads become 3x float4,
// output stores 4x float4.

#define HASH_MASK 0x3FFFFFu
#define P1 19349663u
#define P2 83492791u

__global__ __launch_bounds__(256) void hashed_interp_kernel(
    const float4* __restrict__ pos4,   // (B*3/4) float4 view of (B,3) f32
    const float* __restrict__ table,   // (2^22, 4) f32
    float4* __restrict__ out4,         // (B) float4 view of (B,4) f32
    int nthreads)                      // B/4
{
    int t = blockIdx.x * 256 + threadIdx.x;
    if (t >= nthreads) return;

    // 4 points = 12 floats = 3 float4 loads, fully coalesced & aligned
    float4 a = pos4[3 * (size_t)t + 0];
    float4 b = pos4[3 * (size_t)t + 1];
    float4 c = pos4[3 * (size_t)t + 2];

    float px[4] = {a.x, a.w, b.z, c.y};
    float py[4] = {a.y, b.x, b.w, c.z};
    float pz[4] = {a.z, b.y, c.x, c.w};

    const float inv = 1.0f / 128.0f;  // exact

    uint32_t hx0[4], hx1[4], hy0[4], hy1[4], hz0[4], hz1[4];
    float w0x[4], w1x[4], w0y[4], w1y[4], w0z[4], w1z[4];

#pragma unroll
    for (int p = 0; p < 4; ++p) {
        int lx = (int)floorf(px[p] * 128.0f);
        int ly = (int)floorf(py[p] * 128.0f);
        int lz = (int)floorf(pz[p] * 128.0f);

        w0x[p] = (px[p] - (float)lx * inv) * 128.0f;
        w1x[p] = ((float)(lx + 1) * inv - px[p]) * 128.0f;
        w0y[p] = (py[p] - (float)ly * inv) * 128.0f;
        w1y[p] = ((float)(ly + 1) * inv - py[p]) * 128.0f;
        w0z[p] = (pz[p] - (float)lz * inv) * 128.0f;
        w1z[p] = ((float)(lz + 1) * inv - pz[p]) * 128.0f;

        hx0[p] = (uint32_t)lx;              // prime = 1
        hx1[p] = (uint32_t)(lx + 1);
        hy0[p] = (uint32_t)ly * P1;
        hy1[p] = (uint32_t)(ly + 1) * P1;
        hz0[p] = (uint32_t)lz * P2;
        hz1[p] = (uint32_t)(lz + 1) * P2;
    }

    float acc[4][4];
#pragma unroll
    for (int p = 0; p < 4; ++p)
#pragma unroll
        for (int f = 0; f < 4; ++f) acc[p][f] = 0.f;

    // 32 independent gathers; compiler hoists loads across points for MLP
#pragma unroll
    for (int p = 0; p < 4; ++p) {
#pragma unroll
        for (int cidx = 0; cidx < 8; ++cidx) {
            int bx = (cidx >> 2) & 1;
            int by = (cidx >> 1) & 1;
            int bz = cidx & 1;
            uint32_t h = ((bx ? hx1[p] : hx0[p]) ^ (by ? hy1[p] : hy0[p]) ^
                          (bz ? hz1[p] : hz0[p])) & HASH_MASK;
            const float4 v = *reinterpret_cast<const float4*>(table + (size_t)h * 4);
            float w = ((bx ? w1x[p] : w0x[p]) * (by ? w1y[p] : w0y[p])) *
                      (bz ? w1z[p] : w0z[p]);
            acc[p][0] += v.x * w;
            acc[p][1] += v.y * w;
            acc[p][2] += v.z * w;
            acc[p][3] += v.w * w;
        }
    }

#pragma unroll
    for (int p = 0; p < 4; ++p)
        out4[4 * (size_t)t + p] = make_float4(acc[p][0], acc[p][1], acc[p][2], acc[p][3]);
}

extern "C" void kernel_launch(void* const* d_in, const int* in_sizes, int n_in,
                              void* d_out, int out_size, void* d_ws, size_t ws_size,
                              hipStream_t stream) {
    const float4* pos4 = (const float4*)d_in[0];   // (2^21, 3) f32
    const float* table = (const float*)d_in[1];    // (2^22, 4) f32
    float4* out4 = (float4*)d_out;                 // (2^21, 4) f32

    int batch = in_sizes[0] / 3;       // 2^21
    int nthreads = batch / 4;          // 524288, exact
    int blocks = (nthreads + 255) / 256;
    hashed_interp_kernel<<<blocks, 256, 0, stream>>>(pos4, table, out4, nthreads);
}